// Round 2
// baseline (262.559 us; speedup 1.0000x reference)
//
#include <hip/hip_runtime.h>

// SpaceGroupDenseLayer — real part:
//   out[b,n,f] = sum_i xr[b,n,i]*wr[sg,i,f] - xi[b,n,i]*wi[sg,i,f] + br[sg,f]
// Recast as bf16 MFMA GEMM with concat-K=512:  A=[xr | -xi] (256x512), B=[wr;wi] (512x512).
// Block = 256 thr (4 waves), tile 128(M) x 128(F), BK=64, 8 K-stages, single LDS buffer.
// Wave tile 64x64 = 4x4 frags of v_mfma_f32_16x16x32_bf16.
//   A-frag: A[m=lane&15][k=quad*8+j]; B-frag: B[k=quad*8+j][n=lane&15];
//   C/D: col=lane&15, row=quad*4+reg   (m89/m91-verified layouts).
// fp32->bf16 conversion fused into staging; minus on xi folds into cvt source.
// W ([k][f] in memory) is transposed into LDS via 8k x 4f register micro-tiles.
// Grid = 64 batches x 2 m-blocks x 4 f-blocks = 512 blocks (2/CU, all resident).
//
// R1: XCD-aware bijective blockIdx swizzle — all 8 blocks of a batch on one
// XCD; batch working set (x 512KB + w 1MB) L2-resident. (−7 us measured.)
//
// R2: T14 async-STAGE split. Old loop was serial per stage:
//   load -> pack -> LDS write -> bar -> MFMA -> bar  (8x raw load latency).
// New loop prefetches stage s+1 into registers BEFORE the MFMA of stage s,
// so the ~900cy HBM / ~200cy L2 latency hides under ~1200cy of matrix work:
//   pack+write(s) -> bar -> issue loads(s+1) -> MFMA(s) -> bar.
// Single LDS buffer unchanged (writes stay after the post-MFMA barrier).

#define BB 64
#define NN 256
#define KK 256
#define FF 512
#define NSG 230
#define BM 128
#define BF 128
#define BK 64
#define PITCH 72   // ushorts per LDS row: 64 + 8 pad -> 144 B rows (16B-aligned)

typedef __attribute__((ext_vector_type(8))) short bf16x8;
typedef __attribute__((ext_vector_type(4))) float f32x4;

#if __has_builtin(__builtin_amdgcn_cvt_pk_bf16_f32)
typedef __bf16 bf16x2_t __attribute__((ext_vector_type(2)));
__device__ __forceinline__ unsigned pack_bf16(float a, float b) {
    bf16x2_t r = __builtin_amdgcn_cvt_pk_bf16_f32(a, b);
    return __builtin_bit_cast(unsigned, r);
}
#else
__device__ __forceinline__ unsigned pack_bf16(float a, float b) {
    unsigned ua = __float_as_uint(a);
    unsigned ub = __float_as_uint(b);
    ua += 0x7fffu + ((ua >> 16) & 1u);   // RNE
    ub += 0x7fffu + ((ub >> 16) & 1u);
    return (ua >> 16) | (ub & 0xffff0000u);
}
#endif

__global__ __launch_bounds__(256, 2) void sg_dense_mfma(
    const float* __restrict__ xr_g, const float* __restrict__ xi_g,
    const int* __restrict__ sg_g,
    const float* __restrict__ wr_g, const float* __restrict__ wi_g,
    const float* __restrict__ br_g,
    float* __restrict__ out, const int out_elems)
{
    __shared__ alignas(16) unsigned short As[BM * PITCH];  // [m][k]  18 KB
    __shared__ alignas(16) unsigned short Bs[BF * PITCH];  // [f][k] (transposed) 18 KB

    const int tid = threadIdx.x;

    // ---- XCD-aware bijective swizzle (512 blocks, 8 XCDs, 64 slots/XCD) ----
    const int bx   = blockIdx.x;
    const int xcd  = bx & 7;
    const int slot = bx >> 3;
    const int b    = xcd + ((slot >> 3) << 3);
    const int inner = slot & 7;
    const int mblk = inner & 1;
    const int fblk = inner >> 1;
    const int n0 = mblk * BM;
    const int f0 = fblk * BF;

    int sg = sg_g[b];
    sg = (sg < 0) ? 0 : ((sg >= NSG) ? (NSG - 1) : sg);  // fault-proofing clamp

    const float* __restrict__ wr = wr_g + (size_t)sg * KK * FF;
    const float* __restrict__ wi = wi_g + (size_t)sg * KK * FF;

    // staging indices
    const int ar  = tid >> 1;            // A row 0..127
    const int ah  = (tid & 1) * 32;      // A k-offset {0,32}
    const int bkg = tid >> 5;            // B k-group 0..7  (8 k-rows each)
    const int bfg = tid & 31;            // B f-group 0..31 (4 f-cols each)

    // wave / fragment indices
    const int lane = tid & 63;
    const int wv   = tid >> 6;
    const int wm   = (wv & 1) * 64;      // wave m-offset in tile
    const int wf   = (wv >> 1) * 64;     // wave f-offset in tile
    const int fr   = lane & 15;
    const int quad = lane >> 4;

    f32x4 acc[4][4];
    #pragma unroll
    for (int i = 0; i < 4; ++i)
        #pragma unroll
        for (int j = 0; j < 4; ++j)
            acc[i][j] = (f32x4){0.f, 0.f, 0.f, 0.f};

    // prefetch registers for one stage (A: 8 float4, B: 8 float4)
    float4 va[8], vb[8];

    // ---- issue global loads for stage s into va/vb ----
    #define ISSUE_LOADS(s_)                                                     \
    {                                                                           \
        const int k0_ = (s_) * BK;                                              \
        const bool sec_ = (k0_ >= KK);                                          \
        const int kq_ = k0_ & (KK - 1);                                         \
        const float* srcA_ = (sec_ ? xi_g : xr_g)                               \
                           + ((size_t)(b * NN + n0 + ar) * KK + kq_ + ah);      \
        _Pragma("unroll")                                                       \
        for (int q = 0; q < 8; ++q) va[q] = ((const float4*)srcA_)[q];          \
        const float* srcB_ = (sec_ ? wi : wr)                                   \
                           + (size_t)(kq_ + bkg * 8) * FF + f0 + bfg * 4;       \
        _Pragma("unroll")                                                       \
        for (int j = 0; j < 8; ++j)                                             \
            vb[j] = *(const float4*)(srcB_ + (size_t)j * FF);                   \
    }

    ISSUE_LOADS(0)

    for (int s = 0; s < 8; ++s) {
        const bool second = (s * BK >= KK);   // imag half of concat-K

        // ---- pack prefetched regs and write to LDS ----
        {
            unsigned pk[16];
            if (!second) {
                #pragma unroll
                for (int q = 0; q < 8; ++q) {
                    pk[2*q]   = pack_bf16(va[q].x, va[q].y);
                    pk[2*q+1] = pack_bf16(va[q].z, va[q].w);
                }
            } else {  // A = -xi : sign folds into cvt src modifier
                #pragma unroll
                for (int q = 0; q < 8; ++q) {
                    pk[2*q]   = pack_bf16(-va[q].x, -va[q].y);
                    pk[2*q+1] = pack_bf16(-va[q].z, -va[q].w);
                }
            }
            #pragma unroll
            for (int g = 0; g < 4; ++g) {
                uint4 wv4 = make_uint4(pk[4*g], pk[4*g+1], pk[4*g+2], pk[4*g+3]);
                *(uint4*)&As[ar * PITCH + ah + g * 8] = wv4;
            }

            float ucol[4][8];
            #pragma unroll
            for (int j = 0; j < 8; ++j) {
                ucol[0][j] = vb[j].x; ucol[1][j] = vb[j].y;
                ucol[2][j] = vb[j].z; ucol[3][j] = vb[j].w;
            }
            #pragma unroll
            for (int ff = 0; ff < 4; ++ff) {
                uint4 wv4 = make_uint4(
                    pack_bf16(ucol[ff][0], ucol[ff][1]),
                    pack_bf16(ucol[ff][2], ucol[ff][3]),
                    pack_bf16(ucol[ff][4], ucol[ff][5]),
                    pack_bf16(ucol[ff][6], ucol[ff][7]));
                *(uint4*)&Bs[(bfg * 4 + ff) * PITCH + bkg * 8] = wv4;
            }
        }

        __syncthreads();

        // ---- issue next stage's global loads; they complete under the MFMAs ----
        if (s < 7) ISSUE_LOADS(s + 1)

        // ---- MFMA: 2 k-steps x 4x4 frags ----
        #pragma unroll
        for (int kk = 0; kk < BK; kk += 32) {
            bf16x8 af[4], bfr[4];
            #pragma unroll
            for (int i = 0; i < 4; ++i)
                af[i] = *(const bf16x8*)&As[(wm + i*16 + fr) * PITCH + kk + quad * 8];
            #pragma unroll
            for (int j = 0; j < 4; ++j)
                bfr[j] = *(const bf16x8*)&Bs[(wf + j*16 + fr) * PITCH + kk + quad * 8];
            #pragma unroll
            for (int i = 0; i < 4; ++i)
                #pragma unroll
                for (int j = 0; j < 4; ++j)
                    acc[i][j] = __builtin_amdgcn_mfma_f32_16x16x32_bf16(
                                    af[i], bfr[j], acc[i][j], 0, 0, 0);
        }

        __syncthreads();
    }
    #undef ISSUE_LOADS

    // ---- epilogue: bias + guarded stores ----
    #pragma unroll
    for (int j = 0; j < 4; ++j) {
        const int fcol = f0 + wf + j * 16 + fr;
        const float bias = br_g[sg * FF + fcol];
        #pragma unroll
        for (int i = 0; i < 4; ++i) {
            const int nb = n0 + wm + i * 16 + quad * 4;
            #pragma unroll
            for (int r = 0; r < 4; ++r) {
                const long long idx = (long long)(b * NN + nb + r) * FF + fcol;
                if (idx < out_elems) out[idx] = acc[i][j][r] + bias;
            }
        }
    }
}

extern "C" void kernel_launch(void* const* d_in, const int* in_sizes, int n_in,
                              void* d_out, int out_size, void* d_ws, size_t ws_size,
                              hipStream_t stream) {
    const float* xr = (const float*)d_in[0];
    const float* xi = (const float*)d_in[1];
    const int*   sg = (const int*)  d_in[2];
    const float* wr = (const float*)d_in[3];
    const float* wi = (const float*)d_in[4];
    const float* br = (const float*)d_in[5];
    float* out = (float*)d_out;

    dim3 grid(BB * 2 * 4);   // 512 blocks
    dim3 block(256);
    sg_dense_mfma<<<grid, block, 0, stream>>>(xr, xi, sg, wr, wi, br, out, out_size);
}

// Round 3
// 254.244 us; speedup vs baseline: 1.0327x; 1.0327x over previous
//
#include <hip/hip_runtime.h>

// SpaceGroupDenseLayer — real part:
//   out[b,n,f] = sum_i xr[b,n,i]*wr[sg,i,f] - xi[b,n,i]*wi[sg,i,f] + br[sg,f]
// Recast as bf16 MFMA GEMM with concat-K=512:  A=[xr | -xi] (256x512), B=[wr;wi] (512x512).
// Block = 256 thr (4 waves), tile 128(M) x 128(F), BK=64, 8 K-stages.
// Wave tile 64x64 = 4x4 frags of v_mfma_f32_16x16x32_bf16.
//   A-frag: A[m=lane&15][k=quad*8+j]; B-frag: B[k=quad*8+j][n=lane&15];
//   C/D: col=lane&15, row=quad*4+reg   (m89/m91-verified layouts).
// fp32->bf16 conversion fused into staging; minus on xi folds into cvt source.
// W ([k][f] in memory) is transposed into LDS via 8k x 4f register micro-tiles.
// Grid = 64 batches x 2 m-blocks x 4 f-blocks = 512 blocks (2/CU, all resident).
//
// R1: XCD-aware bijective blockIdx swizzle — all 8 blocks of a batch on one
// XCD; batch working set (x 512KB + w 1MB) L2-resident. (−7 us measured.)
// R2: register prefetch of next stage's A/B (T14). NULL — load latency was
// not the bottleneck (compiler/2-blocks-per-CU already hid it).
// R3: DOUBLE-BUFFERED LDS, one barrier per stage (T3-minimum). The 2-barrier
// single-buffer schedule fenced pack (VALU) from MFMA 16x per block; with
// dbuf the write(s+1) goes to the buffer whose readers finished a barrier
// ago, so only ONE drain per stage and pack overlaps MFMA across waves.
// LDS 2 x 36 KB = 72 KB/block (144 KB/CU at 2 blocks — fits 160).
// Also: epilogue bounds-check hoisted to one uniform test, 32-bit offsets.

#define BB 64
#define NN 256
#define KK 256
#define FF 512
#define NSG 230
#define BM 128
#define BF 128
#define BK 64
#define PITCH 72   // ushorts per LDS row: 64 + 8 pad -> 144 B rows (16B-aligned)
#define TILE (BM * PITCH)   // ushorts per A (or B) tile

typedef __attribute__((ext_vector_type(8))) short bf16x8;
typedef __attribute__((ext_vector_type(4))) float f32x4;

#if __has_builtin(__builtin_amdgcn_cvt_pk_bf16_f32)
typedef __bf16 bf16x2_t __attribute__((ext_vector_type(2)));
__device__ __forceinline__ unsigned pack_bf16(float a, float b) {
    bf16x2_t r = __builtin_amdgcn_cvt_pk_bf16_f32(a, b);
    return __builtin_bit_cast(unsigned, r);
}
#else
__device__ __forceinline__ unsigned pack_bf16(float a, float b) {
    unsigned ua = __float_as_uint(a);
    unsigned ub = __float_as_uint(b);
    ua += 0x7fffu + ((ua >> 16) & 1u);   // RNE
    ub += 0x7fffu + ((ub >> 16) & 1u);
    return (ua >> 16) | (ub & 0xffff0000u);
}
#endif

__global__ __launch_bounds__(256, 2) void sg_dense_mfma(
    const float* __restrict__ xr_g, const float* __restrict__ xi_g,
    const int* __restrict__ sg_g,
    const float* __restrict__ wr_g, const float* __restrict__ wi_g,
    const float* __restrict__ br_g,
    float* __restrict__ out, const int out_elems)
{
    __shared__ alignas(16) unsigned short As[2 * TILE];  // [buf][m][k]  2 x 18 KB
    __shared__ alignas(16) unsigned short Bs[2 * TILE];  // [buf][f][k]  2 x 18 KB

    const int tid = threadIdx.x;

    // ---- XCD-aware bijective swizzle (512 blocks, 8 XCDs, 64 slots/XCD) ----
    const int bx   = blockIdx.x;
    const int xcd  = bx & 7;
    const int slot = bx >> 3;
    const int b    = xcd + ((slot >> 3) << 3);
    const int inner = slot & 7;
    const int mblk = inner & 1;
    const int fblk = inner >> 1;
    const int n0 = mblk * BM;
    const int f0 = fblk * BF;

    int sg = sg_g[b];
    sg = (sg < 0) ? 0 : ((sg >= NSG) ? (NSG - 1) : sg);  // fault-proofing clamp

    const float* __restrict__ wr = wr_g + (size_t)sg * KK * FF;
    const float* __restrict__ wi = wi_g + (size_t)sg * KK * FF;

    // staging indices
    const int ar  = tid >> 1;            // A row 0..127
    const int ah  = (tid & 1) * 32;      // A k-offset {0,32}
    const int bkg = tid >> 5;            // B k-group 0..7  (8 k-rows each)
    const int bfg = tid & 31;            // B f-group 0..31 (4 f-cols each)

    // wave / fragment indices
    const int lane = tid & 63;
    const int wv   = tid >> 6;
    const int wm   = (wv & 1) * 64;      // wave m-offset in tile
    const int wf   = (wv >> 1) * 64;     // wave f-offset in tile
    const int fr   = lane & 15;
    const int quad = lane >> 4;

    f32x4 acc[4][4];
    #pragma unroll
    for (int i = 0; i < 4; ++i)
        #pragma unroll
        for (int j = 0; j < 4; ++j)
            acc[i][j] = (f32x4){0.f, 0.f, 0.f, 0.f};

    // prefetch registers for one stage (A: 8 float4, B: 8 float4)
    float4 va[8], vb[8];

    // ---- issue global loads for stage s into va/vb ----
    #define ISSUE_LOADS(s_)                                                     \
    {                                                                           \
        const int k0_ = (s_) * BK;                                              \
        const bool sec_ = (k0_ >= KK);                                          \
        const int kq_ = k0_ & (KK - 1);                                         \
        const float* srcA_ = (sec_ ? xi_g : xr_g)                               \
                           + ((size_t)(b * NN + n0 + ar) * KK + kq_ + ah);      \
        _Pragma("unroll")                                                       \
        for (int q = 0; q < 8; ++q) va[q] = ((const float4*)srcA_)[q];          \
        const float* srcB_ = (sec_ ? wi : wr)                                   \
                           + (size_t)(kq_ + bkg * 8) * FF + f0 + bfg * 4;       \
        _Pragma("unroll")                                                       \
        for (int j = 0; j < 8; ++j)                                             \
            vb[j] = *(const float4*)(srcB_ + (size_t)j * FF);                   \
    }

    // ---- pack va/vb (stage s_) and write into LDS buffer d_ ----
    #define PACK_WRITE(s_, d_)                                                  \
    {                                                                           \
        const bool sec_ = ((s_) * BK >= KK);                                    \
        unsigned short* Ab_ = As + (d_) * TILE;                                 \
        unsigned short* Bb_ = Bs + (d_) * TILE;                                 \
        unsigned pk[16];                                                        \
        if (!sec_) {                                                            \
            _Pragma("unroll")                                                   \
            for (int q = 0; q < 8; ++q) {                                       \
                pk[2*q]   = pack_bf16(va[q].x, va[q].y);                        \
                pk[2*q+1] = pack_bf16(va[q].z, va[q].w);                        \
            }                                                                   \
        } else {                                                                \
            _Pragma("unroll")                                                   \
            for (int q = 0; q < 8; ++q) {                                       \
                pk[2*q]   = pack_bf16(-va[q].x, -va[q].y);                      \
                pk[2*q+1] = pack_bf16(-va[q].z, -va[q].w);                      \
            }                                                                   \
        }                                                                       \
        _Pragma("unroll")                                                       \
        for (int g = 0; g < 4; ++g) {                                           \
            uint4 wv4 = make_uint4(pk[4*g], pk[4*g+1], pk[4*g+2], pk[4*g+3]);   \
            *(uint4*)&Ab_[ar * PITCH + ah + g * 8] = wv4;                       \
        }                                                                       \
        float ucol[4][8];                                                       \
        _Pragma("unroll")                                                       \
        for (int j = 0; j < 8; ++j) {                                           \
            ucol[0][j] = vb[j].x; ucol[1][j] = vb[j].y;                         \
            ucol[2][j] = vb[j].z; ucol[3][j] = vb[j].w;                         \
        }                                                                       \
        _Pragma("unroll")                                                       \
        for (int ff = 0; ff < 4; ++ff) {                                        \
            uint4 wv4 = make_uint4(                                             \
                pack_bf16(ucol[ff][0], ucol[ff][1]),                            \
                pack_bf16(ucol[ff][2], ucol[ff][3]),                            \
                pack_bf16(ucol[ff][4], ucol[ff][5]),                            \
                pack_bf16(ucol[ff][6], ucol[ff][7]));                           \
            *(uint4*)&Bb_[(bfg * 4 + ff) * PITCH + bkg * 8] = wv4;              \
        }                                                                       \
    }

    // ---- prologue: fill buffer 0, start loads for stage 1 ----
    ISSUE_LOADS(0)
    PACK_WRITE(0, 0)
    ISSUE_LOADS(1)
    __syncthreads();

    // ---- main loop: ONE barrier per stage ----
    #pragma unroll 2
    for (int s = 0; s < 8; ++s) {
        const unsigned short* Ab = As + (s & 1) * TILE;
        const unsigned short* Bb = Bs + (s & 1) * TILE;

        // MFMA: 2 k-steps x 4x4 frags (overlaps other waves' pack + in-flight loads)
        #pragma unroll
        for (int kk = 0; kk < BK; kk += 32) {
            bf16x8 af[4], bfr[4];
            #pragma unroll
            for (int i = 0; i < 4; ++i)
                af[i] = *(const bf16x8*)&Ab[(wm + i*16 + fr) * PITCH + kk + quad * 8];
            #pragma unroll
            for (int j = 0; j < 4; ++j)
                bfr[j] = *(const bf16x8*)&Bb[(wf + j*16 + fr) * PITCH + kk + quad * 8];
            #pragma unroll
            for (int i = 0; i < 4; ++i)
                #pragma unroll
                for (int j = 0; j < 4; ++j)
                    acc[i][j] = __builtin_amdgcn_mfma_f32_16x16x32_bf16(
                                    af[i], bfr[j], acc[i][j], 0, 0, 0);
        }

        if (s < 7) {
            // write stage s+1 into the OTHER buffer: its last readers (MFMA s-1)
            // all passed the previous barrier -> safe with a single drain.
            PACK_WRITE(s + 1, (s + 1) & 1)
            if (s < 6) ISSUE_LOADS(s + 2)
            __syncthreads();
        }
    }
    #undef ISSUE_LOADS
    #undef PACK_WRITE

    // ---- epilogue: bias + stores (uniform bounds check hoisted) ----
    const long long blockEnd = (long long)(b * NN + n0 + BM - 1) * FF + f0 + BF - 1;
    if (blockEnd < out_elems) {
        // fast path: 32-bit offsets, no per-element guard
        const unsigned base = (unsigned)(b * NN + n0 + wm + quad * 4) * FF + f0 + wf + fr;
        #pragma unroll
        for (int j = 0; j < 4; ++j) {
            const float bias = br_g[sg * FF + f0 + wf + j * 16 + fr];
            #pragma unroll
            for (int i = 0; i < 4; ++i) {
                #pragma unroll
                for (int r = 0; r < 4; ++r)
                    out[base + (unsigned)(i * 16 + r) * FF + j * 16] = acc[i][j][r] + bias;
            }
        }
    } else {
        #pragma unroll
        for (int j = 0; j < 4; ++j) {
            const int fcol = f0 + wf + j * 16 + fr;
            const float bias = br_g[sg * FF + fcol];
            #pragma unroll
            for (int i = 0; i < 4; ++i) {
                const int nb = n0 + wm + i * 16 + quad * 4;
                #pragma unroll
                for (int r = 0; r < 4; ++r) {
                    const long long idx = (long long)(b * NN + nb + r) * FF + fcol;
                    if (idx < out_elems) out[idx] = acc[i][j][r] + bias;
                }
            }
        }
    }
}

extern "C" void kernel_launch(void* const* d_in, const int* in_sizes, int n_in,
                              void* d_out, int out_size, void* d_ws, size_t ws_size,
                              hipStream_t stream) {
    const float* xr = (const float*)d_in[0];
    const float* xi = (const float*)d_in[1];
    const int*   sg = (const int*)  d_in[2];
    const float* wr = (const float*)d_in[3];
    const float* wi = (const float*)d_in[4];
    const float* br = (const float*)d_in[5];
    float* out = (float*)d_out;

    dim3 grid(BB * 2 * 4);   // 512 blocks
    dim3 block(256);
    sg_dense_mfma<<<grid, block, 0, stream>>>(xr, xi, sg, wr, wi, br, out, out_size);
}

// Round 5
// 254.202 us; speedup vs baseline: 1.0329x; 1.0002x over previous
//
#include <hip/hip_runtime.h>

// SpaceGroupDenseLayer — real part:
//   out[b,n,f] = sum_i xr[b,n,i]*wr[sg,i,f] - xi[b,n,i]*wi[sg,i,f] + br[sg,f]
// Recast as bf16 MFMA GEMM with concat-K=512:  A=[xr | -xi] (256x512), B=[wr;wi] (512x512).
// Block = 256 thr (4 waves), tile 128(M) x 128(F), BK=64, 8 K-stages.
// Wave tile 64x64 = 4x4 frags of v_mfma_f32_16x16x32_bf16.
//   A-frag: A[m=lane&15][k=quad*8+j]; B-frag: B[k=quad*8+j][n=lane&15];
//   C/D: col=lane&15, row=quad*4+reg   (m89/m91-verified layouts).
// fp32->bf16 conversion fused into staging; minus on xi folds into cvt source.
// W ([k][f] in memory) is transposed into LDS via 8k x 4f register micro-tiles.
// Grid = 64 batches x 2 m-blocks x 4 f-blocks = 512 blocks (2/CU, all resident).
//
// R1: XCD-aware bijective blockIdx swizzle — batch working set L2-resident. (−7 us)
// R2: register prefetch of next stage (T14). NULL as placed — see R4.
// R3: double-buffered LDS, ONE barrier per stage. (−8 us)
// R4: fix the barrier-drain defect + T5 setprio.
//   R3 ordering was  MFMA -> PACK -> ISSUE(s+2) -> barrier.  The compiler must
//   emit s_waitcnt vmcnt(0) before s_barrier, so the "prefetched" loads were
//   DRAINED at the very next barrier with all 4 waves parked — the m97-type
//   structural stall (and why R2 was null). New ordering issues loads AFTER
//   the barrier:  MFMA(s) -> PACK(s+1) -> barrier -> ISSUE(s+2); loads now fly
//   under MFMA(s+1) and are consumed by a counted (compiler) waitcnt in
//   PACK(s+2), never by a barrier drain. Plus s_setprio(1) around the MFMA
//   cluster (T5): the dbuf schedule gives wave role-diversity, the measured
//   prerequisite for setprio to pay.
// R5: identical resubmit of R4 — the R4 bench run died to an infra failure
//   ("container failed twice") before the kernel ever executed; schedule
//   re-audited for hazards (none found).

#define BB 64
#define NN 256
#define KK 256
#define FF 512
#define NSG 230
#define BM 128
#define BF 128
#define BK 64
#define PITCH 72   // ushorts per LDS row: 64 + 8 pad -> 144 B rows (16B-aligned)
#define TILE (BM * PITCH)   // ushorts per A (or B) tile

typedef __attribute__((ext_vector_type(8))) short bf16x8;
typedef __attribute__((ext_vector_type(4))) float f32x4;

#if __has_builtin(__builtin_amdgcn_cvt_pk_bf16_f32)
typedef __bf16 bf16x2_t __attribute__((ext_vector_type(2)));
__device__ __forceinline__ unsigned pack_bf16(float a, float b) {
    bf16x2_t r = __builtin_amdgcn_cvt_pk_bf16_f32(a, b);
    return __builtin_bit_cast(unsigned, r);
}
#else
__device__ __forceinline__ unsigned pack_bf16(float a, float b) {
    unsigned ua = __float_as_uint(a);
    unsigned ub = __float_as_uint(b);
    ua += 0x7fffu + ((ua >> 16) & 1u);   // RNE
    ub += 0x7fffu + ((ub >> 16) & 1u);
    return (ua >> 16) | (ub & 0xffff0000u);
}
#endif

__global__ __launch_bounds__(256, 2) void sg_dense_mfma(
    const float* __restrict__ xr_g, const float* __restrict__ xi_g,
    const int* __restrict__ sg_g,
    const float* __restrict__ wr_g, const float* __restrict__ wi_g,
    const float* __restrict__ br_g,
    float* __restrict__ out, const int out_elems)
{
    __shared__ alignas(16) unsigned short As[2 * TILE];  // [buf][m][k]  2 x 18 KB
    __shared__ alignas(16) unsigned short Bs[2 * TILE];  // [buf][f][k]  2 x 18 KB

    const int tid = threadIdx.x;

    // ---- XCD-aware bijective swizzle (512 blocks, 8 XCDs, 64 slots/XCD) ----
    const int bx   = blockIdx.x;
    const int xcd  = bx & 7;
    const int slot = bx >> 3;
    const int b    = xcd + ((slot >> 3) << 3);
    const int inner = slot & 7;
    const int mblk = inner & 1;
    const int fblk = inner >> 1;
    const int n0 = mblk * BM;
    const int f0 = fblk * BF;

    int sg = sg_g[b];
    sg = (sg < 0) ? 0 : ((sg >= NSG) ? (NSG - 1) : sg);  // fault-proofing clamp

    const float* __restrict__ wr = wr_g + (size_t)sg * KK * FF;
    const float* __restrict__ wi = wi_g + (size_t)sg * KK * FF;

    // staging indices
    const int ar  = tid >> 1;            // A row 0..127
    const int ah  = (tid & 1) * 32;      // A k-offset {0,32}
    const int bkg = tid >> 5;            // B k-group 0..7  (8 k-rows each)
    const int bfg = tid & 31;            // B f-group 0..31 (4 f-cols each)

    // wave / fragment indices
    const int lane = tid & 63;
    const int wv   = tid >> 6;
    const int wm   = (wv & 1) * 64;      // wave m-offset in tile
    const int wf   = (wv >> 1) * 64;     // wave f-offset in tile
    const int fr   = lane & 15;
    const int quad = lane >> 4;

    f32x4 acc[4][4];
    #pragma unroll
    for (int i = 0; i < 4; ++i)
        #pragma unroll
        for (int j = 0; j < 4; ++j)
            acc[i][j] = (f32x4){0.f, 0.f, 0.f, 0.f};

    // prefetch registers for one stage (A: 8 float4, B: 8 float4)
    float4 va[8], vb[8];

    // ---- issue global loads for stage s into va/vb ----
    #define ISSUE_LOADS(s_)                                                     \
    {                                                                           \
        const int k0_ = (s_) * BK;                                              \
        const bool sec_ = (k0_ >= KK);                                          \
        const int kq_ = k0_ & (KK - 1);                                         \
        const float* srcA_ = (sec_ ? xi_g : xr_g)                               \
                           + ((size_t)(b * NN + n0 + ar) * KK + kq_ + ah);      \
        _Pragma("unroll")                                                       \
        for (int q = 0; q < 8; ++q) va[q] = ((const float4*)srcA_)[q];          \
        const float* srcB_ = (sec_ ? wi : wr)                                   \
                           + (size_t)(kq_ + bkg * 8) * FF + f0 + bfg * 4;       \
        _Pragma("unroll")                                                       \
        for (int j = 0; j < 8; ++j)                                             \
            vb[j] = *(const float4*)(srcB_ + (size_t)j * FF);                   \
    }

    // ---- pack va/vb (stage s_) and write into LDS buffer d_ ----
    #define PACK_WRITE(s_, d_)                                                  \
    {                                                                           \
        const bool sec_ = ((s_) * BK >= KK);                                    \
        unsigned short* Ab_ = As + (d_) * TILE;                                 \
        unsigned short* Bb_ = Bs + (d_) * TILE;                                 \
        unsigned pk[16];                                                        \
        if (!sec_) {                                                            \
            _Pragma("unroll")                                                   \
            for (int q = 0; q < 8; ++q) {                                       \
                pk[2*q]   = pack_bf16(va[q].x, va[q].y);                        \
                pk[2*q+1] = pack_bf16(va[q].z, va[q].w);                        \
            }                                                                   \
        } else {                                                                \
            _Pragma("unroll")                                                   \
            for (int q = 0; q < 8; ++q) {                                       \
                pk[2*q]   = pack_bf16(-va[q].x, -va[q].y);                      \
                pk[2*q+1] = pack_bf16(-va[q].z, -va[q].w);                      \
            }                                                                   \
        }                                                                       \
        _Pragma("unroll")                                                       \
        for (int g = 0; g < 4; ++g) {                                           \
            uint4 wv4 = make_uint4(pk[4*g], pk[4*g+1], pk[4*g+2], pk[4*g+3]);   \
            *(uint4*)&Ab_[ar * PITCH + ah + g * 8] = wv4;                       \
        }                                                                       \
        float ucol[4][8];                                                       \
        _Pragma("unroll")                                                       \
        for (int j = 0; j < 8; ++j) {                                           \
            ucol[0][j] = vb[j].x; ucol[1][j] = vb[j].y;                         \
            ucol[2][j] = vb[j].z; ucol[3][j] = vb[j].w;                         \
        }                                                                       \
        _Pragma("unroll")                                                       \
        for (int ff = 0; ff < 4; ++ff) {                                        \
            uint4 wv4 = make_uint4(                                             \
                pack_bf16(ucol[ff][0], ucol[ff][1]),                            \
                pack_bf16(ucol[ff][2], ucol[ff][3]),                            \
                pack_bf16(ucol[ff][4], ucol[ff][5]),                            \
                pack_bf16(ucol[ff][6], ucol[ff][7]));                           \
            *(uint4*)&Bb_[(bfg * 4 + ff) * PITCH + bkg * 8] = wv4;              \
        }                                                                       \
    }

    // ---- prologue: fill buffer 0; barrier; THEN start stage-1 loads ----
    // (nothing global is in flight at the barrier -> no vmcnt(0) drain cost)
    ISSUE_LOADS(0)
    PACK_WRITE(0, 0)
    __syncthreads();
    ISSUE_LOADS(1)

    // ---- main loop: ONE barrier per stage; loads issued AFTER the barrier ----
    #pragma unroll 2
    for (int s = 0; s < 8; ++s) {
        const unsigned short* Ab = As + (s & 1) * TILE;
        const unsigned short* Bb = Bs + (s & 1) * TILE;

        // MFMA: 2 k-steps x 4x4 frags; overlaps other waves' pack and the
        // in-flight ISSUE(s+1) loads issued right after the previous barrier.
        __builtin_amdgcn_s_setprio(1);
        #pragma unroll
        for (int kk = 0; kk < BK; kk += 32) {
            bf16x8 af[4], bfr[4];
            #pragma unroll
            for (int i = 0; i < 4; ++i)
                af[i] = *(const bf16x8*)&Ab[(wm + i*16 + fr) * PITCH + kk + quad * 8];
            #pragma unroll
            for (int j = 0; j < 4; ++j)
                bfr[j] = *(const bf16x8*)&Bb[(wf + j*16 + fr) * PITCH + kk + quad * 8];
            #pragma unroll
            for (int i = 0; i < 4; ++i)
                #pragma unroll
                for (int j = 0; j < 4; ++j)
                    acc[i][j] = __builtin_amdgcn_mfma_f32_16x16x32_bf16(
                                    af[i], bfr[j], acc[i][j], 0, 0, 0);
        }
        __builtin_amdgcn_s_setprio(0);

        if (s < 7) {
            // write stage s+1 into the OTHER buffer (its readers finished a
            // barrier ago); the compiler places a counted vmcnt wait here for
            // the ISSUE(s+1) data — per-wave, overlapped, not a barrier drain.
            PACK_WRITE(s + 1, (s + 1) & 1)
            __syncthreads();
            if (s < 6) ISSUE_LOADS(s + 2)   // in flight across MFMA(s+1)
        }
    }
    #undef ISSUE_LOADS
    #undef PACK_WRITE

    // ---- epilogue: bias + stores (uniform bounds check hoisted) ----
    const long long blockEnd = (long long)(b * NN + n0 + BM - 1) * FF + f0 + BF - 1;
    if (blockEnd < out_elems) {
        // fast path: 32-bit offsets, no per-element guard
        const unsigned base = (unsigned)(b * NN + n0 + wm + quad * 4) * FF + f0 + wf + fr;
        #pragma unroll
        for (int j = 0; j < 4; ++j) {
            const float bias = br_g[sg * FF + f0 + wf + j * 16 + fr];
            #pragma unroll
            for (int i = 0; i < 4; ++i) {
                #pragma unroll
                for (int r = 0; r < 4; ++r)
                    out[base + (unsigned)(i * 16 + r) * FF + j * 16] = acc[i][j][r] + bias;
            }
        }
    } else {
        #pragma unroll
        for (int j = 0; j < 4; ++j) {
            const int fcol = f0 + wf + j * 16 + fr;
            const float bias = br_g[sg * FF + fcol];
            #pragma unroll
            for (int i = 0; i < 4; ++i) {
                const int nb = n0 + wm + i * 16 + quad * 4;
                #pragma unroll
                for (int r = 0; r < 4; ++r) {
                    const long long idx = (long long)(b * NN + nb + r) * FF + fcol;
                    if (idx < out_elems) out[idx] = acc[i][j][r] + bias;
                }
            }
        }
    }
}

extern "C" void kernel_launch(void* const* d_in, const int* in_sizes, int n_in,
                              void* d_out, int out_size, void* d_ws, size_t ws_size,
                              hipStream_t stream) {
    const float* xr = (const float*)d_in[0];
    const float* xi = (const float*)d_in[1];
    const int*   sg = (const int*)  d_in[2];
    const float* wr = (const float*)d_in[3];
    const float* wi = (const float*)d_in[4];
    const float* br = (const float*)d_in[5];
    float* out = (float*)d_out;

    dim3 grid(BB * 2 * 4);   // 512 blocks
    dim3 block(256);
    sg_dense_mfma<<<grid, block, 0, stream>>>(xr, xi, sg, wr, wi, br, out, out_size);
}